// Round 2
// baseline (977.683 us; speedup 1.0000x reference)
//
#include <hip/hip_runtime.h>
#include <cmath>
#include <cstdint>

namespace {

constexpr int kLevels = 12;   // MAX_LEVELS=12 -> levels >= 12 are always masked out
constexpr int kFeat = 32;     // NUM_LEVELS * LEVEL_DIM

typedef float f32x4 __attribute__((ext_vector_type(4)));

struct LevelMeta {
  float scale;
  unsigned res;
  unsigned size;
  unsigned off;
};

struct Meta {
  LevelMeta lv[kLevels];
};

}  // namespace

__global__ __launch_bounds__(256) void hash_triplane_fwd(
    const float* __restrict__ xyz,
    const float* __restrict__ txy,
    const float* __restrict__ tyz,
    const float* __restrict__ txz,
    const int* __restrict__ step_ptr,
    float* __restrict__ out,
    int n, Meta meta)
{
  const int i = blockIdx.x * blockDim.x + threadIdx.x;
  if (i >= n) return;

  const int step = *step_ptr;
  int level = step / 1000 + 1;
  level = level > kLevels ? kLevels : level;
  const int active = 2 * level;

  const float px = xyz[3 * i + 0];
  const float py = xyz[3 * i + 1];
  const float pz = xyz[3 * i + 2];

  float acc[2 * kLevels];
#pragma unroll
  for (int k = 0; k < 2 * kLevels; ++k) acc[k] = 0.0f;

  // planes: (x,y)->txy, (y,z)->tyz, (x,z)->txz ; summed in that order like the ref
  for (int p = 0; p < 3; ++p) {
    float c0, c1;
    const float2* tab;
    if (p == 0)      { c0 = px; c1 = py; tab = reinterpret_cast<const float2*>(txy); }
    else if (p == 1) { c0 = py; c1 = pz; tab = reinterpret_cast<const float2*>(tyz); }
    else             { c0 = px; c1 = pz; tab = reinterpret_cast<const float2*>(txz); }

#pragma unroll
    for (int l = 0; l < kLevels; ++l) {
      const float s = meta.lv[l].scale;
      const unsigned res = meta.lv[l].res;
      const unsigned size = meta.lv[l].size;
      const float2* tb = tab + meta.lv[l].off;

      const float posx = fmaf(c0, s, 0.5f);
      const float posy = fmaf(c1, s, 0.5f);
      const float g0x = floorf(posx);
      const float g0y = floorf(posy);
      const float fx = posx - g0x;
      const float fy = posy - g0y;
      const unsigned ix = (unsigned)g0x;
      const unsigned iy = (unsigned)g0y;

      // dense tiled indexing (all active levels have res*res <= size);
      // values are < 2*size, so conditional subtract == the reference's % size
      unsigned i00 = ix + iy * res;
      unsigned i01 = i00 + res;
      unsigned i10 = i00 + 1;
      unsigned i11 = i01 + 1;
      if (i00 >= size) i00 -= size;
      if (i01 >= size) i01 -= size;
      if (i10 >= size) i10 -= size;
      if (i11 >= size) i11 -= size;

      const float2 t00 = tb[i00];
      const float2 t01 = tb[i01];
      const float2 t10 = tb[i10];
      const float2 t11 = tb[i11];

      const float w00 = (1.0f - fx) * (1.0f - fy);
      const float w01 = (1.0f - fx) * fy;
      const float w10 = fx * (1.0f - fy);
      const float w11 = fx * fy;

      acc[2 * l + 0] += w00 * t00.x + w01 * t01.x + w10 * t10.x + w11 * t11.x;
      acc[2 * l + 1] += w00 * t00.y + w01 * t01.y + w10 * t10.y + w11 * t11.y;
    }
  }

  // static level mask (features >= 2*level are zero; features 24..31 always zero)
#pragma unroll
  for (int k = 0; k < 2 * kLevels; ++k)
    if (k >= active) acc[k] = 0.0f;

  f32x4* o4 = reinterpret_cast<f32x4*>(out + (size_t)i * kFeat);
#pragma unroll
  for (int q = 0; q < 6; ++q) {
    f32x4 v;
    v.x = acc[4 * q + 0];
    v.y = acc[4 * q + 1];
    v.z = acc[4 * q + 2];
    v.w = acc[4 * q + 3];
    __builtin_nontemporal_store(v, o4 + q);
  }
  const f32x4 z = {0.0f, 0.0f, 0.0f, 0.0f};
  __builtin_nontemporal_store(z, o4 + 6);
  __builtin_nontemporal_store(z, o4 + 7);
}

extern "C" void kernel_launch(void* const* d_in, const int* in_sizes, int n_in,
                              void* d_out, int out_size, void* d_ws, size_t ws_size,
                              hipStream_t stream) {
  const float* xyz = (const float*)d_in[0];
  const float* txy = (const float*)d_in[1];
  const float* tyz = (const float*)d_in[2];
  const float* txz = (const float*)d_in[3];
  const int* step  = (const int*)d_in[4];
  float* out = (float*)d_out;
  const int n = in_sizes[0] / 3;

  // Replicate _meta() in double precision (matches numpy within margins >= 0.0128
  // to every ceil boundary; far beyond any libm 1-ulp difference).
  Meta meta;
  unsigned off = 0;
  const double pls = std::exp2(std::log2(2048.0 / 16.0) / 15.0);
  for (int l = 0; l < 16; ++l) {
    const double scale = 16.0 * std::pow(pls, (double)l) - 1.0;
    const unsigned res = (unsigned)std::ceil(scale) + 1u;
    unsigned long long params = (unsigned long long)res * (unsigned long long)res;
    if (params > (1ull << 19)) params = (1ull << 19);
    params = ((params + 7ull) / 8ull) * 8ull;  // align to 8
    if (l < kLevels) {
      meta.lv[l].scale = (float)scale;
      meta.lv[l].res = res;
      meta.lv[l].size = (unsigned)params;
      meta.lv[l].off = off;
    }
    off += (unsigned)params;
  }

  dim3 block(256);
  dim3 grid((unsigned)((n + 255) / 256));
  hipLaunchKernelGGL(hash_triplane_fwd, grid, block, 0, stream,
                     xyz, txy, tyz, txz, step, out, n, meta);
}

// Round 3
// 849.671 us; speedup vs baseline: 1.1507x; 1.1507x over previous
//
#include <hip/hip_runtime.h>
#include <cmath>
#include <cstdint>

namespace {

constexpr int kLevels = 12;   // MAX_LEVELS=12 -> levels >= 12 are always masked out
constexpr int kFeat = 32;     // NUM_LEVELS * LEVEL_DIM
constexpr int kBatch = 6;     // levels per load batch (MLP window)

typedef float f32x4 __attribute__((ext_vector_type(4)));
// 8-byte-aligned 16B vector: pair of adjacent float2 table entries
typedef float f32x4u __attribute__((ext_vector_type(4), aligned(8)));

struct LevelMeta {
  float scale;
  unsigned res;
  unsigned size;
  unsigned off;
};

struct Meta {
  LevelMeta lv[kLevels];
};

}  // namespace

__global__ __launch_bounds__(256) void hash_triplane_fwd(
    const float* __restrict__ xyz,
    const float* __restrict__ txy,
    const float* __restrict__ tyz,
    const float* __restrict__ txz,
    const int* __restrict__ step_ptr,
    float* __restrict__ out,
    int n, Meta meta)
{
  const int i = blockIdx.x * blockDim.x + threadIdx.x;
  if (i >= n) return;

  const int step = *step_ptr;
  int level = step / 1000 + 1;
  level = level > kLevels ? kLevels : level;
  const int active = 2 * level;

  const float px = xyz[3 * i + 0];
  const float py = xyz[3 * i + 1];
  const float pz = xyz[3 * i + 2];

  float acc[2 * kLevels];
#pragma unroll
  for (int k = 0; k < 2 * kLevels; ++k) acc[k] = 0.0f;

  // Per plane: two batches of 6 levels. Phase 1 issues all 12 paired gathers
  // (row0 = [t00|t10], row1 = [t01|t11]); phase 2 consumes. This keeps ~12
  // loads in flight per wave instead of ~4 -> latency-bound fix.
  auto do_plane = [&](float c0, float c1, const float* __restrict__ tabf) {
    const float2* __restrict__ tab = reinterpret_cast<const float2*>(tabf);
#pragma unroll
    for (int h = 0; h < kLevels / kBatch; ++h) {
      f32x4 r0[kBatch], r1[kBatch];
      float fxs[kBatch], fys[kBatch];
      unsigned a0[kBatch], a1[kBatch];

#pragma unroll
      for (int j = 0; j < kBatch; ++j) {
        const int l = h * kBatch + j;
        const float s = meta.lv[l].scale;
        const unsigned res = meta.lv[l].res;
        const unsigned size = meta.lv[l].size;
        const float2* tb = tab + meta.lv[l].off;

        const float posx = fmaf(c0, s, 0.5f);
        const float posy = fmaf(c1, s, 0.5f);
        const float g0x = floorf(posx);
        const float g0y = floorf(posy);
        fxs[j] = posx - g0x;
        fys[j] = posy - g0y;
        const unsigned ix = (unsigned)g0x;
        const unsigned iy = (unsigned)g0y;

        // i00 = ix + iy*res <= res^2 - 1 < size: never wraps.
        unsigned i00 = ix + iy * res;
        unsigned i01 = i00 + res;           // < 2*size
        if (i01 >= size) i01 -= size;
        a0[j] = i00;
        a1[j] = i01;
        // paired 16B gathers; reading one float2 past the level region is
        // in-bounds (levels 12..15 follow level 11 in the table)
        r0[j] = *reinterpret_cast<const f32x4u*>(tb + i00);
        r1[j] = *reinterpret_cast<const f32x4u*>(tb + i01);
      }

#pragma unroll
      for (int j = 0; j < kBatch; ++j) {
        const int l = h * kBatch + j;
        const unsigned size = meta.lv[l].size;
        const float2* tb = tab + meta.lv[l].off;
        const float2 tf = *tb;  // uniform scalar load: wrap target is always idx 0

        const float fx = fxs[j];
        const float fy = fys[j];
        // i10 = (i00+1) % size wraps to 0 iff i00 == size-1 (same for i11/i01)
        const bool w0 = (a0[j] == size - 1u);
        const bool w1 = (a1[j] == size - 1u);
        const float t10x = w0 ? tf.x : r0[j].z;
        const float t10y = w0 ? tf.y : r0[j].w;
        const float t11x = w1 ? tf.x : r1[j].z;
        const float t11y = w1 ? tf.y : r1[j].w;

        const float w00 = (1.0f - fx) * (1.0f - fy);
        const float w01 = (1.0f - fx) * fy;
        const float w10 = fx * (1.0f - fy);
        const float w11 = fx * fy;

        acc[2 * l + 0] += w00 * r0[j].x + w01 * r1[j].x + w10 * t10x + w11 * t11x;
        acc[2 * l + 1] += w00 * r0[j].y + w01 * r1[j].y + w10 * t10y + w11 * t11y;
      }
    }
  };

  do_plane(px, py, txy);
  do_plane(py, pz, tyz);
  do_plane(px, pz, txz);

  // static level mask (features >= 2*level are zero; features 24..31 always zero)
#pragma unroll
  for (int k = 0; k < 2 * kLevels; ++k)
    if (k >= active) acc[k] = 0.0f;

  f32x4* o4 = reinterpret_cast<f32x4*>(out + (size_t)i * kFeat);
#pragma unroll
  for (int q = 0; q < 6; ++q) {
    f32x4 v;
    v.x = acc[4 * q + 0];
    v.y = acc[4 * q + 1];
    v.z = acc[4 * q + 2];
    v.w = acc[4 * q + 3];
    __builtin_nontemporal_store(v, o4 + q);
  }
  const f32x4 z = {0.0f, 0.0f, 0.0f, 0.0f};
  __builtin_nontemporal_store(z, o4 + 6);
  __builtin_nontemporal_store(z, o4 + 7);
}

extern "C" void kernel_launch(void* const* d_in, const int* in_sizes, int n_in,
                              void* d_out, int out_size, void* d_ws, size_t ws_size,
                              hipStream_t stream) {
  const float* xyz = (const float*)d_in[0];
  const float* txy = (const float*)d_in[1];
  const float* tyz = (const float*)d_in[2];
  const float* txz = (const float*)d_in[3];
  const int* step  = (const int*)d_in[4];
  float* out = (float*)d_out;
  const int n = in_sizes[0] / 3;

  // Replicate _meta() in double precision (matches numpy: margins >= 0.0128
  // to every ceil boundary, far beyond any libm 1-ulp difference).
  Meta meta;
  unsigned off = 0;
  const double pls = std::exp2(std::log2(2048.0 / 16.0) / 15.0);
  for (int l = 0; l < 16; ++l) {
    const double scale = 16.0 * std::pow(pls, (double)l) - 1.0;
    const unsigned res = (unsigned)std::ceil(scale) + 1u;
    unsigned long long params = (unsigned long long)res * (unsigned long long)res;
    if (params > (1ull << 19)) params = (1ull << 19);
    params = ((params + 7ull) / 8ull) * 8ull;  // align to 8
    if (l < kLevels) {
      meta.lv[l].scale = (float)scale;
      meta.lv[l].res = res;
      meta.lv[l].size = (unsigned)params;
      meta.lv[l].off = off;
    }
    off += (unsigned)params;
  }

  dim3 block(256);
  dim3 grid((unsigned)((n + 255) / 256));
  hipLaunchKernelGGL(hash_triplane_fwd, grid, block, 0, stream,
                     xyz, txy, tyz, txz, step, out, n, meta);
}

// Round 4
// 708.827 us; speedup vs baseline: 1.3793x; 1.1987x over previous
//
#include <hip/hip_runtime.h>
#include <cmath>
#include <cstdint>

namespace {

constexpr int kLevels = 12;   // MAX_LEVELS=12 -> levels >= 12 are always masked out
constexpr int kFeat = 32;     // NUM_LEVELS * LEVEL_DIM
constexpr int kBatch = 6;     // levels per load batch (MLP window)

typedef float f32x4 __attribute__((ext_vector_type(4)));
// 8-byte-aligned 16B vector: pair of adjacent float2 table entries
typedef float f32x4u __attribute__((ext_vector_type(4), aligned(8)));

struct LevelMeta {
  float scale;
  unsigned res;
  unsigned size;
  unsigned off;
};

struct Meta {
  LevelMeta lv[kLevels];
};

}  // namespace

__global__ __launch_bounds__(256) void hash_triplane_fwd(
    const float* __restrict__ xyz,
    const float* __restrict__ txy,
    const float* __restrict__ tyz,
    const float* __restrict__ txz,
    const int* __restrict__ step_ptr,
    float* __restrict__ out,
    int n, Meta meta)
{
  // Per-wave output staging: chunk-major [8 chunks][64 lanes][16B] = 8KB/wave.
  __shared__ float lds[4 * 2048];

  const int tid = threadIdx.x;
  const int wid = tid >> 6;
  const int lane = tid & 63;
  const int bbase = blockIdx.x * 256;
  const int i = bbase + tid;
  const int pi = i < n ? i : (n - 1);  // clamped compute index (no early return: barrier below)

  const int step = *step_ptr;
  int level = step / 1000 + 1;
  level = level > kLevels ? kLevels : level;
  const int active = 2 * level;

  const float px = xyz[3 * pi + 0];
  const float py = xyz[3 * pi + 1];
  const float pz = xyz[3 * pi + 2];

  float acc[2 * kLevels];
#pragma unroll
  for (int k = 0; k < 2 * kLevels; ++k) acc[k] = 0.0f;

  // Per plane: two batches of 6 levels. Phase 1 issues all 12 paired gathers
  // (row0 = [t00|t10], row1 = [t01|t11]); phase 2 consumes.
  auto do_plane = [&](float c0, float c1, const float* __restrict__ tabf) {
    const float2* __restrict__ tab = reinterpret_cast<const float2*>(tabf);
#pragma unroll
    for (int h = 0; h < kLevels / kBatch; ++h) {
      f32x4 r0[kBatch], r1[kBatch];
      float fxs[kBatch], fys[kBatch];
      unsigned wrap0 = 0, wrap1 = 0;  // per-j wrap flags packed into bitmasks

#pragma unroll
      for (int j = 0; j < kBatch; ++j) {
        const int l = h * kBatch + j;
        const float s = meta.lv[l].scale;
        const unsigned res = meta.lv[l].res;
        const unsigned size = meta.lv[l].size;
        const float2* tb = tab + meta.lv[l].off;

        const float posx = fmaf(c0, s, 0.5f);
        const float posy = fmaf(c1, s, 0.5f);
        const float g0x = floorf(posx);
        const float g0y = floorf(posy);
        fxs[j] = posx - g0x;
        fys[j] = posy - g0y;
        const unsigned ix = (unsigned)g0x;
        const unsigned iy = (unsigned)g0y;

        // i00 = ix + iy*res <= res^2 - 1 < size: never wraps.
        unsigned i00 = ix + iy * res;
        unsigned i01 = i00 + res;           // < 2*size
        if (i01 >= size) i01 -= size;
        wrap0 |= (i00 == size - 1u) ? (1u << j) : 0u;
        wrap1 |= (i01 == size - 1u) ? (1u << j) : 0u;
        // paired 16B gathers; reading one float2 past the level region is
        // in-bounds (levels 12..15 follow level 11 in the table)
        r0[j] = *reinterpret_cast<const f32x4u*>(tb + i00);
        r1[j] = *reinterpret_cast<const f32x4u*>(tb + i01);
      }

#pragma unroll
      for (int j = 0; j < kBatch; ++j) {
        const int l = h * kBatch + j;
        const float2* tb = tab + meta.lv[l].off;
        const float2 tf = *tb;  // uniform scalar load: wrap target is always idx 0

        const float fx = fxs[j];
        const float fy = fys[j];
        const bool w0 = (wrap0 >> j) & 1u;
        const bool w1 = (wrap1 >> j) & 1u;
        const float t10x = w0 ? tf.x : r0[j].z;
        const float t10y = w0 ? tf.y : r0[j].w;
        const float t11x = w1 ? tf.x : r1[j].z;
        const float t11y = w1 ? tf.y : r1[j].w;

        const float w00 = (1.0f - fx) * (1.0f - fy);
        const float w01 = (1.0f - fx) * fy;
        const float w10 = fx * (1.0f - fy);
        const float w11 = fx * fy;

        acc[2 * l + 0] += w00 * r0[j].x + w01 * r1[j].x + w10 * t10x + w11 * t11x;
        acc[2 * l + 1] += w00 * r0[j].y + w01 * r1[j].y + w10 * t10y + w11 * t11y;
      }
    }
  };

  do_plane(px, py, txy);
  do_plane(py, pz, tyz);
  do_plane(px, pz, txz);

  // static level mask (features >= 2*level are zero; features 24..31 always zero)
#pragma unroll
  for (int k = 0; k < 2 * kLevels; ++k)
    if (k >= active) acc[k] = 0.0f;

  // ---- stage this wave's 8KB in LDS (chunk-major), then write back with
  // each store instruction covering 1KB CONTIGUOUS (fixes 3x write amp +
  // RMW fetches that thrashed the table working set out of L2/L3) ----
  float* wlds = lds + wid * 2048;
#pragma unroll
  for (int c = 0; c < 8; ++c) {
    f32x4 v;
    v.x = c < 6 ? acc[4 * c + 0] : 0.0f;
    v.y = c < 6 ? acc[4 * c + 1] : 0.0f;
    v.z = c < 6 ? acc[4 * c + 2] : 0.0f;
    v.w = c < 6 ? acc[4 * c + 3] : 0.0f;
    *reinterpret_cast<f32x4*>(wlds + c * 256 + lane * 4) = v;
  }
  __syncthreads();

  const long long wbase = (long long)bbase + wid * 64;
  f32x4* obase = reinterpret_cast<f32x4*>(out) + wbase * 8;
#pragma unroll
  for (int q = 0; q < 8; ++q) {
    const int p = q * 8 + (lane >> 3);   // point within wave
    const int c = lane & 7;              // 16B chunk within point
    const f32x4 v = *reinterpret_cast<const f32x4*>(wlds + c * 256 + p * 4);
    if (wbase + p < n)
      __builtin_nontemporal_store(v, obase + q * 64 + lane);
  }
}

extern "C" void kernel_launch(void* const* d_in, const int* in_sizes, int n_in,
                              void* d_out, int out_size, void* d_ws, size_t ws_size,
                              hipStream_t stream) {
  const float* xyz = (const float*)d_in[0];
  const float* txy = (const float*)d_in[1];
  const float* tyz = (const float*)d_in[2];
  const float* txz = (const float*)d_in[3];
  const int* step  = (const int*)d_in[4];
  float* out = (float*)d_out;
  const int n = in_sizes[0] / 3;

  // Replicate _meta() in double precision (matches numpy: margins >= 0.0128
  // to every ceil boundary, far beyond any libm 1-ulp difference).
  Meta meta;
  unsigned off = 0;
  const double pls = std::exp2(std::log2(2048.0 / 16.0) / 15.0);
  for (int l = 0; l < 16; ++l) {
    const double scale = 16.0 * std::pow(pls, (double)l) - 1.0;
    const unsigned res = (unsigned)std::ceil(scale) + 1u;
    unsigned long long params = (unsigned long long)res * (unsigned long long)res;
    if (params > (1ull << 19)) params = (1ull << 19);
    params = ((params + 7ull) / 8ull) * 8ull;  // align to 8
    if (l < kLevels) {
      meta.lv[l].scale = (float)scale;
      meta.lv[l].res = res;
      meta.lv[l].size = (unsigned)params;
      meta.lv[l].off = off;
    }
    off += (unsigned)params;
  }

  dim3 block(256);
  dim3 grid((unsigned)((n + 255) / 256));
  hipLaunchKernelGGL(hash_triplane_fwd, grid, block, 0, stream,
                     xyz, txy, tyz, txz, step, out, n, meta);
}

// Round 5
// 556.122 us; speedup vs baseline: 1.7580x; 1.2746x over previous
//
#include <hip/hip_runtime.h>
#include <cmath>
#include <cstdint>

namespace {

constexpr int kLevels = 12;   // MAX_LEVELS=12 -> levels >= 12 are always masked out
constexpr int kFeat = 32;     // NUM_LEVELS * LEVEL_DIM
constexpr int kBatch = 6;     // levels per load batch (MLP window)
constexpr unsigned kNB = 32768;  // 32^3 Morton buckets (5 bits/axis)

typedef float f32x4 __attribute__((ext_vector_type(4)));
// 8-byte-aligned 16B vector: pair of adjacent float2 table entries
typedef float f32x4u __attribute__((ext_vector_type(4), aligned(8)));

struct LevelMeta {
  float scale;
  unsigned res;
  unsigned size;
  unsigned off;
};

struct Meta {
  LevelMeta lv[kLevels];
};

__device__ inline unsigned spread5(unsigned v) {
  v &= 31u;
  v = (v | (v << 8)) & 0x0000100Fu;
  v = (v | (v << 4)) & 0x000010C3u;
  v = (v | (v << 2)) & 0x00001249u;
  return v;
}

__device__ inline unsigned bucket_of(float x, float y, float z) {
  unsigned xi = (unsigned)fminf(fmaxf(x * 32.0f, 0.0f), 31.0f);
  unsigned yi = (unsigned)fminf(fmaxf(y * 32.0f, 0.0f), 31.0f);
  unsigned zi = (unsigned)fminf(fmaxf(z * 32.0f, 0.0f), 31.0f);
  return spread5(xi) | (spread5(yi) << 1) | (spread5(zi) << 2);
}

// Shared bilinear-gather core over one plane, batched for MLP.
template <typename AccFn>
__device__ inline void gather_planes(float px, float py, float pz,
                                     const float* __restrict__ txy,
                                     const float* __restrict__ tyz,
                                     const float* __restrict__ txz,
                                     const Meta& meta, float* acc) {
  auto do_plane = [&](float c0, float c1, const float* __restrict__ tabf) {
    const float2* __restrict__ tab = reinterpret_cast<const float2*>(tabf);
#pragma unroll
    for (int h = 0; h < kLevels / kBatch; ++h) {
      f32x4 r0[kBatch], r1[kBatch];
      float fxs[kBatch], fys[kBatch];
      unsigned wrap0 = 0, wrap1 = 0;

#pragma unroll
      for (int j = 0; j < kBatch; ++j) {
        const int l = h * kBatch + j;
        const float s = meta.lv[l].scale;
        const unsigned res = meta.lv[l].res;
        const unsigned size = meta.lv[l].size;
        const float2* tb = tab + meta.lv[l].off;

        const float posx = fmaf(c0, s, 0.5f);
        const float posy = fmaf(c1, s, 0.5f);
        const float g0x = floorf(posx);
        const float g0y = floorf(posy);
        fxs[j] = posx - g0x;
        fys[j] = posy - g0y;
        const unsigned ix = (unsigned)g0x;
        const unsigned iy = (unsigned)g0y;

        unsigned i00 = ix + iy * res;        // < size always
        unsigned i01 = i00 + res;            // < 2*size
        if (i01 >= size) i01 -= size;
        wrap0 |= (i00 == size - 1u) ? (1u << j) : 0u;
        wrap1 |= (i01 == size - 1u) ? (1u << j) : 0u;
        r0[j] = *reinterpret_cast<const f32x4u*>(tb + i00);
        r1[j] = *reinterpret_cast<const f32x4u*>(tb + i01);
      }

#pragma unroll
      for (int j = 0; j < kBatch; ++j) {
        const int l = h * kBatch + j;
        const float2* tb = tab + meta.lv[l].off;
        const float2 tf = *tb;  // wrap target is always idx 0

        const float fx = fxs[j];
        const float fy = fys[j];
        const bool w0 = (wrap0 >> j) & 1u;
        const bool w1 = (wrap1 >> j) & 1u;
        const float t10x = w0 ? tf.x : r0[j].z;
        const float t10y = w0 ? tf.y : r0[j].w;
        const float t11x = w1 ? tf.x : r1[j].z;
        const float t11y = w1 ? tf.y : r1[j].w;

        const float w00 = (1.0f - fx) * (1.0f - fy);
        const float w01 = (1.0f - fx) * fy;
        const float w10 = fx * (1.0f - fy);
        const float w11 = fx * fy;

        acc[2 * l + 0] += w00 * r0[j].x + w01 * r1[j].x + w10 * t10x + w11 * t11x;
        acc[2 * l + 1] += w00 * r0[j].y + w01 * r1[j].y + w10 * t10y + w11 * t11y;
      }
    }
  };
  do_plane(px, py, txy);
  do_plane(py, pz, tyz);
  do_plane(px, pz, txz);
}

}  // namespace

// ---------------- sort prefix ----------------

__global__ __launch_bounds__(256) void k_hist(const float* __restrict__ xyz,
                                              unsigned* __restrict__ counts, int n) {
  const int i = blockIdx.x * blockDim.x + threadIdx.x;
  if (i >= n) return;
  atomicAdd(&counts[bucket_of(xyz[3 * i], xyz[3 * i + 1], xyz[3 * i + 2])], 1u);
}

__global__ __launch_bounds__(1024) void k_scan(const unsigned* __restrict__ counts,
                                               unsigned* __restrict__ cursor) {
  __shared__ unsigned part[1024];
  const int t = threadIdx.x;
  const int base = t * 32;
  unsigned loc[32];
  unsigned run = 0;
#pragma unroll
  for (int j = 0; j < 32; ++j) { loc[j] = run; run += counts[base + j]; }
  part[t] = run;
  __syncthreads();
  for (int off = 1; off < 1024; off <<= 1) {
    unsigned v = (t >= off) ? part[t - off] : 0u;
    __syncthreads();
    part[t] += v;
    __syncthreads();
  }
  const unsigned ebase = part[t] - run;  // exclusive base for this thread's run
#pragma unroll
  for (int j = 0; j < 32; ++j) cursor[base + j] = ebase + loc[j];
}

__global__ __launch_bounds__(256) void k_scatter(const float* __restrict__ xyz,
                                                 unsigned* __restrict__ cursor,
                                                 f32x4* __restrict__ sorted, int n) {
  const int i = blockIdx.x * blockDim.x + threadIdx.x;
  if (i >= n) return;
  const float x = xyz[3 * i], y = xyz[3 * i + 1], z = xyz[3 * i + 2];
  const unsigned pos = atomicAdd(&cursor[bucket_of(x, y, z)], 1u);
  f32x4 v;
  v.x = x; v.y = y; v.z = z; v.w = __uint_as_float((unsigned)i);
  sorted[pos] = v;
}

// ---------------- main gather (sorted points, scatter output rows) ----------------

__global__ __launch_bounds__(256) void k_main_sorted(
    const f32x4* __restrict__ sorted,
    const float* __restrict__ txy,
    const float* __restrict__ tyz,
    const float* __restrict__ txz,
    const int* __restrict__ step_ptr,
    float* __restrict__ out,
    int n, Meta meta)
{
  // [4 waves][8 chunks][260 floats] (+4 pad per chunk row: bank decorrelation)
  __shared__ float lds[4 * 8 * 260];
  __shared__ unsigned idxs[256];

  const int tid = threadIdx.x;
  const int wid = tid >> 6;
  const int lane = tid & 63;
  const int g = blockIdx.x * 256 + tid;
  const bool valid = g < n;
  const f32x4 s = sorted[valid ? g : (n - 1)];
  const unsigned row = valid ? __float_as_uint(s.w) : 0xFFFFFFFFu;

  const int step = *step_ptr;
  int level = step / 1000 + 1;
  level = level > kLevels ? kLevels : level;
  const int active = 2 * level;

  float acc[2 * kLevels];
#pragma unroll
  for (int k = 0; k < 2 * kLevels; ++k) acc[k] = 0.0f;

  gather_planes<int>(s.x, s.y, s.z, txy, tyz, txz, meta, acc);

#pragma unroll
  for (int k = 0; k < 2 * kLevels; ++k)
    if (k >= active) acc[k] = 0.0f;

  // stage 8KB/wave in LDS, then each store instruction covers 8 whole
  // 128B output rows (one line each) -> no write amplification
  float* wlds = lds + wid * (8 * 260);
#pragma unroll
  for (int c = 0; c < 8; ++c) {
    f32x4 v;
    v.x = c < 6 ? acc[4 * c + 0] : 0.0f;
    v.y = c < 6 ? acc[4 * c + 1] : 0.0f;
    v.z = c < 6 ? acc[4 * c + 2] : 0.0f;
    v.w = c < 6 ? acc[4 * c + 3] : 0.0f;
    *reinterpret_cast<f32x4*>(wlds + c * 260 + lane * 4) = v;
  }
  idxs[tid] = row;
  __syncthreads();

#pragma unroll
  for (int q = 0; q < 8; ++q) {
    const int p = q * 8 + (lane >> 3);   // point within wave
    const int c = lane & 7;              // 16B chunk within row
    const unsigned r = idxs[wid * 64 + p];
    const f32x4 v = *reinterpret_cast<const f32x4*>(wlds + c * 260 + p * 4);
    if (r != 0xFFFFFFFFu)
      __builtin_nontemporal_store(v, reinterpret_cast<f32x4*>(out) + (size_t)r * 8 + c);
  }
}

// ---------------- fallback (R4 kernel) if ws too small ----------------

__global__ __launch_bounds__(256) void k_fused_linear(
    const float* __restrict__ xyz,
    const float* __restrict__ txy,
    const float* __restrict__ tyz,
    const float* __restrict__ txz,
    const int* __restrict__ step_ptr,
    float* __restrict__ out,
    int n, Meta meta)
{
  __shared__ float lds[4 * 2048];
  const int tid = threadIdx.x;
  const int wid = tid >> 6;
  const int lane = tid & 63;
  const int bbase = blockIdx.x * 256;
  const int i = bbase + tid;
  const int pi = i < n ? i : (n - 1);

  const int step = *step_ptr;
  int level = step / 1000 + 1;
  level = level > kLevels ? kLevels : level;
  const int active = 2 * level;

  float acc[2 * kLevels];
#pragma unroll
  for (int k = 0; k < 2 * kLevels; ++k) acc[k] = 0.0f;

  gather_planes<int>(xyz[3 * pi], xyz[3 * pi + 1], xyz[3 * pi + 2],
                     txy, tyz, txz, meta, acc);

#pragma unroll
  for (int k = 0; k < 2 * kLevels; ++k)
    if (k >= active) acc[k] = 0.0f;

  float* wlds = lds + wid * 2048;
#pragma unroll
  for (int c = 0; c < 8; ++c) {
    f32x4 v;
    v.x = c < 6 ? acc[4 * c + 0] : 0.0f;
    v.y = c < 6 ? acc[4 * c + 1] : 0.0f;
    v.z = c < 6 ? acc[4 * c + 2] : 0.0f;
    v.w = c < 6 ? acc[4 * c + 3] : 0.0f;
    *reinterpret_cast<f32x4*>(wlds + c * 256 + lane * 4) = v;
  }
  __syncthreads();

  const long long wbase = (long long)bbase + wid * 64;
  f32x4* obase = reinterpret_cast<f32x4*>(out) + wbase * 8;
#pragma unroll
  for (int q = 0; q < 8; ++q) {
    const int p = q * 8 + (lane >> 3);
    const int c = lane & 7;
    const f32x4 v = *reinterpret_cast<const f32x4*>(wlds + c * 256 + p * 4);
    if (wbase + p < n)
      __builtin_nontemporal_store(v, obase + q * 64 + lane);
  }
}

extern "C" void kernel_launch(void* const* d_in, const int* in_sizes, int n_in,
                              void* d_out, int out_size, void* d_ws, size_t ws_size,
                              hipStream_t stream) {
  const float* xyz = (const float*)d_in[0];
  const float* txy = (const float*)d_in[1];
  const float* tyz = (const float*)d_in[2];
  const float* txz = (const float*)d_in[3];
  const int* step  = (const int*)d_in[4];
  float* out = (float*)d_out;
  const int n = in_sizes[0] / 3;

  // Replicate _meta() in double precision (matches numpy: margins >= 0.0128
  // to every ceil boundary, far beyond any libm 1-ulp difference).
  Meta meta;
  unsigned off = 0;
  const double pls = std::exp2(std::log2(2048.0 / 16.0) / 15.0);
  for (int l = 0; l < 16; ++l) {
    const double scale = 16.0 * std::pow(pls, (double)l) - 1.0;
    const unsigned res = (unsigned)std::ceil(scale) + 1u;
    unsigned long long params = (unsigned long long)res * (unsigned long long)res;
    if (params > (1ull << 19)) params = (1ull << 19);
    params = ((params + 7ull) / 8ull) * 8ull;  // align to 8
    if (l < kLevels) {
      meta.lv[l].scale = (float)scale;
      meta.lv[l].res = res;
      meta.lv[l].size = (unsigned)params;
      meta.lv[l].off = off;
    }
    off += (unsigned)params;
  }

  const dim3 block(256);
  const dim3 grid((unsigned)((n + 255) / 256));

  // ws layout: [counts: kNB u32][cursor: kNB u32][pad to 256KB][sorted: n f32x4]
  const size_t sorted_off = 256 * 1024;
  const size_t need = sorted_off + (size_t)n * sizeof(f32x4);

  if (ws_size >= need) {
    unsigned* counts = (unsigned*)d_ws;
    unsigned* cursor = counts + kNB;
    f32x4* sorted = (f32x4*)((char*)d_ws + sorted_off);

    hipMemsetAsync(counts, 0, kNB * sizeof(unsigned), stream);
    hipLaunchKernelGGL(k_hist, grid, block, 0, stream, xyz, counts, n);
    hipLaunchKernelGGL(k_scan, dim3(1), dim3(1024), 0, stream, counts, cursor);
    hipLaunchKernelGGL(k_scatter, grid, block, 0, stream, xyz, cursor, sorted, n);
    hipLaunchKernelGGL(k_main_sorted, grid, block, 0, stream,
                       sorted, txy, tyz, txz, step, out, n, meta);
  } else {
    hipLaunchKernelGGL(k_fused_linear, grid, block, 0, stream,
                       xyz, txy, tyz, txz, step, out, n, meta);
  }
}